// Round 1
// 257.127 us; speedup vs baseline: 1.0314x; 1.0314x over previous
//
#include <hip/hip_runtime.h>

typedef _Float16 f16;
typedef f16 f16x8 __attribute__((ext_vector_type(8)));
typedef f16 f16x4v __attribute__((ext_vector_type(4)));
typedef float f32x4 __attribute__((ext_vector_type(4)));

// async global->LDS, 16B per lane. LDS dest is wave-uniform base; HW scatters
// lane i's 16B to base + i*16.
__device__ __forceinline__ void async_ld16(const void* g, void* l) {
    __builtin_amdgcn_global_load_lds(
        (const __attribute__((address_space(1))) unsigned int*)g,
        (__attribute__((address_space(3))) unsigned int*)l, 16, 0, 0);
}

// ============================================================================
// r8: QKV projection rewritten as a 256x256-tile 8-phase kernel (T1+T2+T3+T4+T5
// per the technique catalog). C[8192 x 3072] = inp16 @ W3^T + bias; segment
// epilogues: Q/K row-major f16 (+bias), V transposed to [b][e][s] via LDS.
//
// Geometry: BM=BN=256, BK=64 (2 x kk-32 halves), 512 thr = 8 waves (2M x 4N),
// per-wave C = 128x64 = 8x4 fragments of 16x16x32 f16 MFMA. LDS = 2 buffers x
// (A 256x64 + B 256x64) f16 = 128 KiB. K = 1024 = 16 K-tiles, 2 per iteration.
//
// T2 swizzle: LDS rows are 64 B (32 f16); 16B-unit u of row holds global unit
// c = u ^ ((row>>1)&3). Fragment reads (stride-64B rows, fixed k-col) then
// cover all 8 bank positions uniformly per quarter-wave batch -> conflict-free.
// global_load_lds dest stays LINEAR; the SOURCE col is pre-swizzled per lane
// (m173 both-sides-or-neither rule).
//
// Schedule (phases p0..p7 per iteration; tile 2i in buf0, 2i+1 in buf1):
//   compute: p0 b0.kk0.n01 | p1 b0.kk0.n23 | p2 b0.kk1.n01 | p3 b0.kk1.n23
//            p4..p7 same on buf1.
//   stage:   p0 b1.A.k1<-t+1 | p1 b1.B.k1<-t+1 | p2 b0.A.k0<-t+2 | p3 b0.B.k0
//            p4 b0.A.k1<-t+2 | p5 b0.B.k1<-t+2 | p6 b1.A.k0<-t+3 | p7 b1.B.k0
//   Every overwrite is issued >=1 full phase (2+ barriers) after the region's
//   last ds_read; counted s_waitcnt vmcnt(4) at p3/p7 ONLY (T4) -> 2 half-
//   tiles always in flight across each group boundary, never drained mid-loop.
// ============================================================================
__global__ __launch_bounds__(512, 2) void qkv256(
    const f16* __restrict__ A, const f16* __restrict__ Bt,
    const float* __restrict__ b_q, const float* __restrict__ b_k,
    const float* __restrict__ b_v,
    f16* __restrict__ Q16, f16* __restrict__ K16, f16* __restrict__ Vt16)
{
    constexpr int LDA = 1024;
    // T1: XCD-aware bijective swizzle (grid 384, 384 % 8 == 0). Each XCD gets
    // 4 consecutive M-panels x all 12 N-tiles -> A-panel reuse in its L2.
    int bid = blockIdx.x;
    bid = (bid & 7) * 48 + (bid >> 3);
    const int by = bid / 12, bx = bid - by * 12;
    const int mBase = by * 256, nBase = bx * 256;

    __shared__ __align__(16) f16 smem[65536];  // 128 KiB

    const int tid = threadIdx.x;
    const int wave = tid >> 6, lane = tid & 63;
    const int wrow = wave >> 2, wcol = wave & 3;
    const int quad = lane >> 4, l16 = lane & 15;

    // staging: lane tid covers LDS (row = tid>>2 (+128/round), unit u = tid&3);
    // pre-swizzled source unit c = u ^ ((row>>1)&3) = (tid&3) ^ ((tid>>3)&3)
    const int rowLane = tid >> 2;
    const int cOff = ((tid & 3) ^ ((tid >> 3) & 3)) * 8;
    const f16* pA  = A  + (long)(mBase + rowLane) * LDA + cOff;
    const f16* pA1 = pA + 128 * LDA;
    const f16* pB  = Bt + (long)(nBase + rowLane) * LDA + cOff;
    const f16* pB1 = pB + 128 * LDA;
    const int stgBase = wave * 1024;   // byte offset inside an 8 KiB round

    // ds_read byte offsets, swizzled unit within the 64 B row
    const int swz  = (quad ^ ((l16 >> 1) & 3)) * 16;
    const int aOff = (wrow * 128 + l16) * 64 + swz;
    const int bOff = (wcol * 64 + l16) * 64 + swz;

    f32x4 acc[8][4];
#pragma unroll
    for (int m = 0; m < 8; ++m)
#pragma unroll
        for (int n = 0; n < 4; ++n) acc[m][n] = (f32x4){0.f, 0.f, 0.f, 0.f};
    f16x8 af[8], bf[4];

// region byte offsets: buf b: b*65536; op (A=0,B=1): op*32768; k-half: kh*16384
#define STG(b, op, kh, P, P1, tOff) do {                                        \
    char* d_ = (char*)smem + (b) * 65536 + (op) * 32768 + (kh) * 16384 + stgBase; \
    async_ld16((P)  + (tOff) * 64 + (kh) * 32, d_);                             \
    async_ld16((P1) + (tOff) * 64 + (kh) * 32, d_ + 8192);                      \
} while (0)
#define RD_A(b, kk) do {                                                        \
    const char* s_ = (const char*)smem + (b) * 65536 + (kk) * 16384 + aOff;     \
    _Pragma("unroll") for (int m_ = 0; m_ < 8; ++m_)                            \
        af[m_] = *(const f16x8*)(s_ + m_ * 1024);                               \
} while (0)
#define RD_B2(b, kk, n0_) do {                                                  \
    const char* s_ = (const char*)smem + (b) * 65536 + 32768 + (kk) * 16384 + bOff; \
    bf[(n0_)]     = *(const f16x8*)(s_ + ((n0_)) * 1024);                       \
    bf[(n0_) + 1] = *(const f16x8*)(s_ + ((n0_) + 1) * 1024);                   \
} while (0)
// barrier; lgkmcnt(0)+sched_barrier (rule #18); setprio'd 16-MFMA cluster (T5)
#define FENCE_MM(n0_) do {                                                      \
    __builtin_amdgcn_s_barrier();                                               \
    asm volatile("s_waitcnt lgkmcnt(0)" ::: "memory");                          \
    __builtin_amdgcn_sched_barrier(0);                                          \
    __builtin_amdgcn_s_setprio(1);                                              \
    _Pragma("unroll") for (int m_ = 0; m_ < 8; ++m_) {                          \
        acc[m_][(n0_)]     = __builtin_amdgcn_mfma_f32_16x16x32_f16(af[m_], bf[(n0_)],     acc[m_][(n0_)],     0, 0, 0); \
        acc[m_][(n0_) + 1] = __builtin_amdgcn_mfma_f32_16x16x32_f16(af[m_], bf[(n0_) + 1], acc[m_][(n0_) + 1], 0, 0, 0); \
    }                                                                           \
    __builtin_amdgcn_s_setprio(0);                                              \
} while (0)
#define VMC(n) asm volatile("s_waitcnt vmcnt(" #n ")" ::: "memory")
#define BAR __builtin_amdgcn_s_barrier()

    // prologue: tile0 (all 4 halves) + tile1 (k0 halves); wait tile0 landed
    STG(0, 0, 0, pA, pA1, 0); STG(0, 1, 0, pB, pB1, 0);
    STG(0, 0, 1, pA, pA1, 0); STG(0, 1, 1, pB, pB1, 0);
    STG(1, 0, 0, pA, pA1, 1); STG(1, 1, 0, pB, pB1, 1);
    VMC(4);
    BAR;

#pragma unroll 1
    for (int i = 0; i < 7; ++i) {
        RD_A(0, 0); RD_B2(0, 0, 0); STG(1, 0, 1, pA, pA1, 1);   // p0
        FENCE_MM(0); BAR;
        RD_B2(0, 0, 2);             STG(1, 1, 1, pB, pB1, 1);   // p1
        FENCE_MM(2); BAR;
        RD_A(0, 1); RD_B2(0, 1, 0); STG(0, 0, 0, pA, pA1, 2);   // p2
        FENCE_MM(0); BAR;
        RD_B2(0, 1, 2);             STG(0, 1, 0, pB, pB1, 2);   // p3
        FENCE_MM(2); VMC(4); BAR;
        RD_A(1, 0); RD_B2(1, 0, 0); STG(0, 0, 1, pA, pA1, 2);   // p4
        FENCE_MM(0); BAR;
        RD_B2(1, 0, 2);             STG(0, 1, 1, pB, pB1, 2);   // p5
        FENCE_MM(2); BAR;
        RD_A(1, 1); RD_B2(1, 1, 0); STG(1, 0, 0, pA, pA1, 3);   // p6
        FENCE_MM(0); BAR;
        RD_B2(1, 1, 2);             STG(1, 1, 0, pB, pB1, 3);   // p7
        FENCE_MM(2); VMC(4); BAR;
        pA += 128; pA1 += 128; pB += 128; pB1 += 128;
    }
    // peeled tail (tiles 14,15): only tile15's k1 halves left to stage
    RD_A(0, 0); RD_B2(0, 0, 0); STG(1, 0, 1, pA, pA1, 1);
    FENCE_MM(0); BAR;
    RD_B2(0, 0, 2);             STG(1, 1, 1, pB, pB1, 1);
    FENCE_MM(2); BAR;
    RD_A(0, 1); RD_B2(0, 1, 0);
    FENCE_MM(0); BAR;
    RD_B2(0, 1, 2);
    FENCE_MM(2); VMC(0); BAR;
    RD_A(1, 0); RD_B2(1, 0, 0);
    FENCE_MM(0); BAR;
    RD_B2(1, 0, 2);
    FENCE_MM(2); BAR;
    RD_A(1, 1); RD_B2(1, 1, 0);
    FENCE_MM(0); BAR;
    RD_B2(1, 1, 2);
    FENCE_MM(2); BAR;   // trailing barrier also guards smem reuse below

    // ---- epilogue. C/D layout: col = lane&15, row = quad*4 + reg  [m89] ----
    const int seg = nBase >> 10;
    const float* bs = (seg == 0) ? b_q : (seg == 1) ? b_k : b_v;
    const int lcb = (nBase & 1023) + wcol * 64;
    float bvv[4];
#pragma unroll
    for (int n = 0; n < 4; ++n) bvv[n] = bs[lcb + n * 16 + l16];

    if (seg < 2) {
        f16* dst = (seg == 0) ? Q16 : K16;
#pragma unroll
        for (int m = 0; m < 8; ++m)
#pragma unroll
            for (int n = 0; n < 4; ++n)
#pragma unroll
                for (int r = 0; r < 4; ++r) {
                    const int row = mBase + wrow * 128 + m * 16 + quad * 4 + r;
                    dst[(long)row * 1024 + lcb + n * 16 + l16] =
                        (f16)(acc[m][n][r] + bvv[n]);
                }
    } else {
        // V: per-wave transpose through a private LDS region (64 e x 80 f16,
        // 160 B rows keep 16B-aligned b128 reads), store 8 e-rows x 128 B per
        // wave-instr along s. Intra-wave only -> no cross-wave barriers.
        const int b = mBase >> 11, s0 = mBase & 2047;
        const int e0 = (nBase & 1023) + wcol * 64;
        f16* epiW = smem + wave * (64 * 80);
#pragma unroll
        for (int sb = 0; sb < 2; ++sb) {
#pragma unroll
            for (int m4 = 0; m4 < 4; ++m4)
#pragma unroll
                for (int n = 0; n < 4; ++n) {
                    f16x4v pk;
#pragma unroll
                    for (int r = 0; r < 4; ++r)
                        pk[r] = (f16)(acc[sb * 4 + m4][n][r] + bvv[n]);
                    *(f16x4v*)&epiW[(n * 16 + l16) * 80 + m4 * 16 + quad * 4] = pk;
                }
            asm volatile("s_waitcnt lgkmcnt(0)" ::: "memory");
#pragma unroll
            for (int it = 0; it < 8; ++it) {
                const int e = it * 8 + (lane >> 3);
                const f16x8 v = *(const f16x8*)&epiW[e * 80 + (lane & 7) * 8];
                *(f16x8*)(Vt16 + ((long)b * 1024 + e0 + e) * 2048 + s0 +
                          wrow * 128 + sb * 64 + (lane & 7) * 8) = v;
            }
        }
    }
#undef STG
#undef RD_A
#undef RD_B2
#undef FENCE_MM
#undef VMC
#undef BAR
}

// ============================================================================
// modes 2/3 (scores / PV) unchanged from r7 -- next optimization target.
// ============================================================================
// C[m,n] = sum_k A[m,k] * Bt[n,k], tile 128 x 128, K-step 64 = 2 x BK32.
// MODE 2: 512 thr (8 waves, 32x64/wave). P[q][k] = exp(score/32) f16,
//         causal-zeroed; rowsum atomics.
// MODE 3: 512 thr. out = (P @ V) / rowsum[q], fp32; K-loop causal-limited.
template <int MODE>
__global__ __launch_bounds__((MODE == 0) ? 256 : 512) void gemm_bt(
    const f16* __restrict__ A, long strideAb, int lda,
    const f16* __restrict__ Bt, long strideBb, int ldb,
    const float* __restrict__ b_q, const float* __restrict__ b_k,
    const float* __restrict__ b_v, float* __restrict__ rowsum,
    void* __restrict__ C0, void* __restrict__ C1, void* __restrict__ C2,
    long strideCb, int K,
    const int* __restrict__ maskedp)
{
    constexpr int NT  = (MODE == 0) ? 256 : 512;   // threads
    constexpr int NI  = (MODE == 0) ? 4 : 2;       // 16-row blocks per wave
    constexpr int RND = (128 * 32) / (NT * 8);     // staging rounds per subtile

    const int bx = blockIdx.x, bz = blockIdx.z;
    // heavy (long-K / unskipped) rows launch first for causal modes
    const int by = (MODE >= 2) ? (gridDim.y - 1 - blockIdx.y) : blockIdx.y;
    const int masked = maskedp ? *maskedp : 1;
    if (MODE == 2 && masked && bx > by) return;      // fully-masked tile
    int kmax = K;
    if (MODE == 3 && masked) kmax = min(K, (by + 1) * 128);

    A  += (long)bz * strideAb;
    Bt += (long)bz * strideBb;

    // two BK=32 sub-tiles of A (128x32) + two of B (128x32)
    __shared__ __align__(16) f16 smem[256 * 64];
    f16* sA = smem;                    // halves at h*4096
    f16* sB = smem + 128 * 64;

    const int tid  = threadIdx.x;
    const int wave = tid >> 6, lane = tid & 63;
    const int wrow = wave >> 1, wcol = wave & 1;
    const int quad = lane >> 4, l16 = lane & 15;
    const int mBase = by * 128, nBase = bx * 128;

    f32x4 acc[NI][4];
#pragma unroll
    for (int i = 0; i < NI; ++i)
#pragma unroll
        for (int j = 0; j < 4; ++j)
            acc[i][j] = (f32x4){0.f, 0.f, 0.f, 0.f};

    // pointer-bumped staging addresses (+64 f16 per outer iter)
    const f16* aP[RND];
    const f16* bP[RND];
#pragma unroll
    for (int r = 0; r < RND; ++r) {
        aP[r] = A  + (long)(mBase + ((r * NT + tid) >> 2)) * lda + ((tid * 8) & 31);
        bP[r] = Bt + (long)(nBase + ((r * NT + tid) >> 2)) * ldb + ((tid * 8) & 31);
    }
    const int ldsOff = wave * 512;

    const int nT = kmax >> 6;          // K-step 64
    for (int kt = 0; kt < nT; ++kt) {
#pragma unroll
        for (int h = 0; h < 2; ++h)
#pragma unroll
            for (int r = 0; r < RND; ++r) {
                async_ld16(aP[r] + h * 32, &sA[h * 4096 + r * (NT * 8) + ldsOff]);
                async_ld16(bP[r] + h * 32, &sB[h * 4096 + r * (NT * 8) + ldsOff]);
            }
#pragma unroll
        for (int r = 0; r < RND; ++r) { aP[r] += 64; bP[r] += 64; }
        __syncthreads();

#pragma unroll
        for (int h = 0; h < 2; ++h) {
            f16x8 af[NI], bf[4];
#pragma unroll
            for (int i = 0; i < NI; ++i)
                af[i] = *(const f16x8*)&sA[h * 4096 + (wrow * (16 * NI) + i * 16 + l16) * 32 + quad * 8];
#pragma unroll
            for (int j = 0; j < 4; ++j)
                bf[j] = *(const f16x8*)&sB[h * 4096 + (wcol * 64 + j * 16 + l16) * 32 + quad * 8];
#pragma unroll
            for (int i = 0; i < NI; ++i)
#pragma unroll
                for (int j = 0; j < 4; ++j)
                    acc[i][j] = __builtin_amdgcn_mfma_f32_16x16x32_f16(af[i], bf[j], acc[i][j], 0, 0, 0);
        }
        __syncthreads();
    }

    // ---- epilogues. C/D layout: col = lane&15, row = quad*4 + reg  [m89] ----
    if (MODE == 0) {
        const int seg = nBase >> 10;
        const float* bs = (seg == 0) ? b_q : (seg == 1) ? b_k : b_v;
        const int lcb = (nBase & 1023) + wcol * 64;
        float bvv[4];
#pragma unroll
        for (int j = 0; j < 4; ++j) bvv[j] = bs[lcb + j * 16 + l16];

        if (seg < 2) {
            f16* dst = (seg == 0) ? (f16*)C0 : (f16*)C1;
#pragma unroll
            for (int i = 0; i < 4; ++i)
#pragma unroll
                for (int j = 0; j < 4; ++j)
#pragma unroll
                    for (int r = 0; r < 4; ++r) {
                        const int row = mBase + wrow * 64 + i * 16 + quad * 4 + r;
                        dst[(long)row * 1024 + lcb + j * 16 + l16] = (f16)(acc[i][j][r] + bvv[j]);
                    }
        } else {
            // V: transpose tile through LDS, store coalesced along s.
            const int b = mBase >> 11, s0 = mBase & 2047;
            f16* epiT = smem;   // 64 x 136 f16
#pragma unroll
            for (int h = 0; h < 2; ++h) {
                if (wcol == h) {
#pragma unroll
                    for (int i = 0; i < 4; ++i)
#pragma unroll
                        for (int j = 0; j < 4; ++j) {
                            f16x4v pk;
#pragma unroll
                            for (int r = 0; r < 4; ++r)
                                pk[r] = (f16)(acc[i][j][r] + bvv[j]);
                            *(f16x4v*)&epiT[(j * 16 + l16) * 136 + wrow * 64 + i * 16 + quad * 4] = pk;
                        }
                }
                __syncthreads();
                const int er = tid >> 2;
                f16* dst = (f16*)C2 +
                    ((long)b * 1024 + (nBase & 1023) + h * 64 + er) * 2048 + s0;
#pragma unroll
                for (int cc = 0; cc < 4; ++cc) {
                    const int ch = (tid & 3) + cc * 4;
                    *(f16x8*)&dst[ch * 8] = *(const f16x8*)&epiT[er * 136 + ch * 8];
                }
                __syncthreads();
            }
        }
    } else if (MODE == 2) {
        f16* Crow = (f16*)C0 + (long)bz * strideCb;
        float* rsb = rowsum + bz * 2048;
#pragma unroll
        for (int i = 0; i < NI; ++i) {
            float rs[4] = {0.f, 0.f, 0.f, 0.f};
#pragma unroll
            for (int j = 0; j < 4; ++j)
#pragma unroll
                for (int r = 0; r < 4; ++r) {
                    const int row = mBase + wrow * 32 + i * 16 + quad * 4 + r;
                    const int col = nBase + wcol * 64 + j * 16 + l16;
                    float e = __expf(acc[i][j][r] * 0.03125f);
                    if (masked && col > row) e = 0.f;
                    const f16 hv = (f16)e;
                    Crow[(long)row * 2048 + col] = hv;
                    rs[r] += (float)hv;
                }
#pragma unroll
            for (int r = 0; r < 4; ++r) {
                float s = rs[r];
                s += __shfl_xor(s, 1);
                s += __shfl_xor(s, 2);
                s += __shfl_xor(s, 4);
                s += __shfl_xor(s, 8);
                if (l16 == 0) {
                    const int row = mBase + wrow * 32 + i * 16 + quad * 4 + r;
                    atomicAdd(&rsb[row], s);
                }
            }
        }
    } else {  // MODE 3
        float* Crow = (float*)C0 + (long)bz * strideCb;
        const float* rsb = rowsum + bz * 2048;
#pragma unroll
        for (int i = 0; i < NI; ++i)
#pragma unroll
            for (int r = 0; r < 4; ++r) {
                const int row = mBase + wrow * 32 + i * 16 + quad * 4 + r;
                const float inv = 1.f / rsb[row];
#pragma unroll
                for (int j = 0; j < 4; ++j) {
                    const int col = nBase + wcol * 64 + j * 16 + l16;
                    Crow[(long)row * 1024 + col] = acc[i][j][r] * inv;
                }
            }
    }
}

__global__ void cvt_inp(const float* __restrict__ in, f16* __restrict__ out, int n4)
{
    const int i = blockIdx.x * blockDim.x + threadIdx.x;
    if (i >= n4) return;
    const float4 v = ((const float4*)in)[i];
    f16x4v o;
    o[0] = (f16)v.x; o[1] = (f16)v.y; o[2] = (f16)v.z; o[3] = (f16)v.w;
    ((f16x4v*)out)[i] = o;
}

// three 1024x1024 weight matrices -> contiguous f16 [3072][1024]
__global__ void cvt_w3(const float* __restrict__ W0, const float* __restrict__ W1,
                       const float* __restrict__ W2, f16* __restrict__ out)
{
    const int bxx = blockIdx.x;            // 3072 blocks
    const int which = bxx >> 10;
    const float* src = (which == 0) ? W0 : (which == 1) ? W1 : W2;
    const int i = (bxx & 1023) * 256 + threadIdx.x;
    const float4 v = ((const float4*)src)[i];
    f16x4v o;
    o[0] = (f16)v.x; o[1] = (f16)v.y; o[2] = (f16)v.z; o[3] = (f16)v.w;
    ((f16x4v*)(out + (long)which * 1024 * 1024))[i] = o;
}

extern "C" void kernel_launch(void* const* d_in, const int* in_sizes, int n_in,
                              void* d_out, int out_size, void* d_ws, size_t ws_size,
                              hipStream_t stream)
{
    const float* inp = (const float*)d_in[0];
    const int* masked = (const int*)d_in[1];
    const float* Wq = (const float*)d_in[2];
    const float* bq = (const float*)d_in[3];
    const float* Wk = (const float*)d_in[4];
    const float* bk = (const float*)d_in[5];
    const float* Wv = (const float*)d_in[6];
    const float* bv = (const float*)d_in[7];
    float* out = (float*)d_out;

    const int Bb = 4, S = 2048, E = 1024;
    const long nTok = (long)Bb * S;   // 8192

    // workspace (~102 MB). W3 segments must stay contiguous (one Bt operand).
    char* ws = (char*)d_ws;
    f16* inp16 = (f16*)ws;   ws += nTok * E * 2;         // 16 MB
    f16* W3    = (f16*)ws;   ws += (long)3 * E * E * 2;  //  6 MB
    f16* Q16   = (f16*)ws;   ws += nTok * E * 2;         // 16 MB
    f16* K16   = (f16*)ws;   ws += nTok * E * 2;         // 16 MB
    f16* Vt16  = (f16*)ws;   ws += nTok * E * 2;         // 16 MB ([b][e][s])
    f16* P16   = (f16*)ws;   ws += (long)Bb * S * S * 2; // 32 MB
    float* rsum = (float*)ws; ws += nTok * 4;            // 32 KB

    dim3 blk(256);

    hipMemsetAsync(rsum, 0, nTok * 4, stream);
    cvt_inp<<<(int)(nTok * E / 4 / 256), blk, 0, stream>>>(inp, inp16, (int)(nTok * E / 4));
    cvt_w3<<<3 * 1024, blk, 0, stream>>>(Wq, Wk, Wv, W3);

    // fused QKV: 256x256-tile 8-phase kernel (r8)
    qkv256<<<dim3(32 * 12), dim3(512), 0, stream>>>(
        inp16, W3, bq, bk, bv, Q16, K16, Vt16);

    // P = exp(QK^T/32) + rowsum atomics (128x128 tiles, 8-wave blocks,
    // causal skip, heavy rows first)
    gemm_bt<2><<<dim3(S / 128, S / 128, Bb), dim3(512), 0, stream>>>(
        Q16, (long)S * E, E, K16, (long)S * E, E, nullptr, nullptr, nullptr, rsum,
        P16, nullptr, nullptr, (long)S * S, E, masked);

    // out = (P @ V)/rowsum (128x128 tiles, 8-wave blocks, K causal-limited)
    gemm_bt<3><<<dim3(E / 128, S / 128, Bb), dim3(512), 0, stream>>>(
        P16, (long)S * S, S, Vt16, (long)E * S, S, nullptr, nullptr, nullptr, rsum,
        out, nullptr, nullptr, (long)S * E, S, masked);
}

// Round 2
// 244.187 us; speedup vs baseline: 1.0860x; 1.0530x over previous
//
#include <hip/hip_runtime.h>

typedef _Float16 f16;
typedef f16 f16x8 __attribute__((ext_vector_type(8)));
typedef f16 f16x4v __attribute__((ext_vector_type(4)));
typedef float f32x4 __attribute__((ext_vector_type(4)));

// async global->LDS, 16B per lane. LDS dest is wave-uniform base; HW scatters
// lane i's 16B to base + i*16.
__device__ __forceinline__ void async_ld16(const void* g, void* l) {
    __builtin_amdgcn_global_load_lds(
        (const __attribute__((address_space(1))) unsigned int*)g,
        (__attribute__((address_space(3))) unsigned int*)l, 16, 0, 0);
}

// ============================================================================
// 256x256-tile 8-phase GEMM loop (T1..T5), shared by qkv256 and scores256.
// Geometry: BM=BN=256, BK=64 (2 x kk-32 halves), 512 thr = 8 waves (2M x 4N),
// per-wave C = 128x64 = 8x4 frags of 16x16x32 f16 MFMA. LDS = 2 buf x
// (A 256x64 + B 256x64) f16 = 128 KiB. K = 1024 = 16 K-tiles, 2 per iter.
//
// T2 swizzle: LDS rows are 64 B; 16B-unit u of row holds global unit
// c = u ^ ((row>>1)&3); global_load_lds dest LINEAR, source col pre-swizzled
// (m173 both-sides rule). r8 measured: bank conflicts 6.55M -> 524K.
//
// Schedule: 8 phases / 2 K-tiles; stage one (buf,op,khalf) region per phase;
// counted s_waitcnt vmcnt(4) at p3/p7 ONLY (2 half-tile regions stay in
// flight across each boundary, never drained mid-loop).
// ============================================================================

// region byte offsets: buf b: b*65536; op (A=0,B=1): op*32768; k-half: kh*16384
#define STG(b, op, kh, P, P1, tOff) do {                                        \
    char* d_ = (char*)smem + (b) * 65536 + (op) * 32768 + (kh) * 16384 + stgBase; \
    async_ld16((P)  + (tOff) * 64 + (kh) * 32, d_);                             \
    async_ld16((P1) + (tOff) * 64 + (kh) * 32, d_ + 8192);                      \
} while (0)
#define RD_A(b, kk) do {                                                        \
    const char* s_ = (const char*)smem + (b) * 65536 + (kk) * 16384 + aOff;     \
    _Pragma("unroll") for (int m_ = 0; m_ < 8; ++m_)                            \
        af[m_] = *(const f16x8*)(s_ + m_ * 1024);                               \
} while (0)
#define RD_B2(b, kk, n0_) do {                                                  \
    const char* s_ = (const char*)smem + (b) * 65536 + 32768 + (kk) * 16384 + bOff; \
    bf[(n0_)]     = *(const f16x8*)(s_ + ((n0_)) * 1024);                       \
    bf[(n0_) + 1] = *(const f16x8*)(s_ + ((n0_) + 1) * 1024);                   \
} while (0)
// barrier; lgkmcnt(0)+sched_barrier (rule #18); setprio'd 16-MFMA cluster (T5)
#define FENCE_MM(n0_) do {                                                      \
    __builtin_amdgcn_s_barrier();                                               \
    asm volatile("s_waitcnt lgkmcnt(0)" ::: "memory");                          \
    __builtin_amdgcn_sched_barrier(0);                                          \
    __builtin_amdgcn_s_setprio(1);                                              \
    _Pragma("unroll") for (int m_ = 0; m_ < 8; ++m_) {                          \
        acc[m_][(n0_)]     = __builtin_amdgcn_mfma_f32_16x16x32_f16(af[m_], bf[(n0_)],     acc[m_][(n0_)],     0, 0, 0); \
        acc[m_][(n0_) + 1] = __builtin_amdgcn_mfma_f32_16x16x32_f16(af[m_], bf[(n0_) + 1], acc[m_][(n0_) + 1], 0, 0, 0); \
    }                                                                           \
    __builtin_amdgcn_s_setprio(0);                                              \
} while (0)
#define VMC(n) asm volatile("s_waitcnt vmcnt(" #n ")" ::: "memory")
#define BAR __builtin_amdgcn_s_barrier()

// 7 steady iterations + peeled tail = 16 K-tiles (K=1024, lda=ldb=1024).
#define GEMM256_MAIN_LOOP do {                                                  \
    STG(0, 0, 0, pA, pA1, 0); STG(0, 1, 0, pB, pB1, 0);                         \
    STG(0, 0, 1, pA, pA1, 0); STG(0, 1, 1, pB, pB1, 0);                         \
    STG(1, 0, 0, pA, pA1, 1); STG(1, 1, 0, pB, pB1, 1);                         \
    VMC(4);                                                                     \
    BAR;                                                                        \
    _Pragma("unroll 1")                                                         \
    for (int i_ = 0; i_ < 7; ++i_) {                                            \
        RD_A(0, 0); RD_B2(0, 0, 0); STG(1, 0, 1, pA, pA1, 1);   /* p0 */        \
        FENCE_MM(0); BAR;                                                       \
        RD_B2(0, 0, 2);             STG(1, 1, 1, pB, pB1, 1);   /* p1 */        \
        FENCE_MM(2); BAR;                                                       \
        RD_A(0, 1); RD_B2(0, 1, 0); STG(0, 0, 0, pA, pA1, 2);   /* p2 */        \
        FENCE_MM(0); BAR;                                                       \
        RD_B2(0, 1, 2);             STG(0, 1, 0, pB, pB1, 2);   /* p3 */        \
        FENCE_MM(2); VMC(4); BAR;                                               \
        RD_A(1, 0); RD_B2(1, 0, 0); STG(0, 0, 1, pA, pA1, 2);   /* p4 */        \
        FENCE_MM(0); BAR;                                                       \
        RD_B2(1, 0, 2);             STG(0, 1, 1, pB, pB1, 2);   /* p5 */        \
        FENCE_MM(2); BAR;                                                       \
        RD_A(1, 1); RD_B2(1, 1, 0); STG(1, 0, 0, pA, pA1, 3);   /* p6 */        \
        FENCE_MM(0); BAR;                                                       \
        RD_B2(1, 1, 2);             STG(1, 1, 0, pB, pB1, 3);   /* p7 */        \
        FENCE_MM(2); VMC(4); BAR;                                               \
        pA += 128; pA1 += 128; pB += 128; pB1 += 128;                           \
    }                                                                           \
    RD_A(0, 0); RD_B2(0, 0, 0); STG(1, 0, 1, pA, pA1, 1);                       \
    FENCE_MM(0); BAR;                                                           \
    RD_B2(0, 0, 2);             STG(1, 1, 1, pB, pB1, 1);                       \
    FENCE_MM(2); BAR;                                                           \
    RD_A(0, 1); RD_B2(0, 1, 0);                                                 \
    FENCE_MM(0); BAR;                                                           \
    RD_B2(0, 1, 2);                                                             \
    FENCE_MM(2); VMC(0); BAR;                                                   \
    RD_A(1, 0); RD_B2(1, 0, 0);                                                 \
    FENCE_MM(0); BAR;                                                           \
    RD_B2(1, 0, 2);                                                             \
    FENCE_MM(2); BAR;                                                           \
    RD_A(1, 1); RD_B2(1, 1, 0);                                                 \
    FENCE_MM(0); BAR;                                                           \
    RD_B2(1, 1, 2);                                                             \
    FENCE_MM(2); BAR;  /* trailing barrier also guards smem reuse below */      \
} while (0)

// common per-thread index setup (names used by the macros above)
#define GEMM256_SETUP                                                           \
    __shared__ __align__(16) f16 smem[65536];  /* 128 KiB */                    \
    const int tid = threadIdx.x;                                                \
    const int wave = tid >> 6, lane = tid & 63;                                 \
    const int wrow = wave >> 2, wcol = wave & 3;                                \
    const int quad = lane >> 4, l16 = lane & 15;                                \
    const int rowLane = tid >> 2;                                               \
    const int cOff = ((tid & 3) ^ ((tid >> 3) & 3)) * 8;                        \
    const int stgBase = wave * 1024;                                            \
    const int swz  = (quad ^ ((l16 >> 1) & 3)) * 16;                            \
    const int aOff = (wrow * 128 + l16) * 64 + swz;                             \
    const int bOff = (wcol * 64 + l16) * 64 + swz;                              \
    f32x4 acc[8][4];                                                            \
    _Pragma("unroll") for (int m_i = 0; m_i < 8; ++m_i)                         \
        _Pragma("unroll") for (int n_i = 0; n_i < 4; ++n_i)                     \
            acc[m_i][n_i] = (f32x4){0.f, 0.f, 0.f, 0.f};                        \
    f16x8 af[8], bf[4];

// ============================================================================
// r8: fused QKV projection. C[8192 x 3072] = inp16 @ W3^T + bias; segment
// epilogues: Q/K row-major f16 (+bias), V transposed to [b][e][s] via LDS.
// KNOWN ISSUE (r9 post-mortem): grid 384 @ 1 block/CU = 1.5 rounds -> 2
// serialized rounds (33% tail). Fix deferred to keep this round single-change.
// ============================================================================
__global__ __launch_bounds__(512, 2) void qkv256(
    const f16* __restrict__ A, const f16* __restrict__ Bt,
    const float* __restrict__ b_q, const float* __restrict__ b_k,
    const float* __restrict__ b_v,
    f16* __restrict__ Q16, f16* __restrict__ K16, f16* __restrict__ Vt16)
{
    // T1: XCD-aware bijective swizzle (grid 384, 384 % 8 == 0).
    int bid = blockIdx.x;
    bid = (bid & 7) * 48 + (bid >> 3);
    const int by = bid / 12, bx = bid - by * 12;
    const int mBase = by * 256, nBase = bx * 256;

    GEMM256_SETUP

    const f16* pA  = A  + (long)(mBase + rowLane) * 1024 + cOff;
    const f16* pA1 = pA + 128 * 1024;
    const f16* pB  = Bt + (long)(nBase + rowLane) * 1024 + cOff;
    const f16* pB1 = pB + 128 * 1024;

    GEMM256_MAIN_LOOP;

    // ---- epilogue. C/D layout: col = lane&15, row = quad*4 + reg  [m89] ----
    const int seg = nBase >> 10;
    const float* bs = (seg == 0) ? b_q : (seg == 1) ? b_k : b_v;
    const int lcb = (nBase & 1023) + wcol * 64;
    float bvv[4];
#pragma unroll
    for (int n = 0; n < 4; ++n) bvv[n] = bs[lcb + n * 16 + l16];

    if (seg < 2) {
        f16* dst = (seg == 0) ? Q16 : K16;
#pragma unroll
        for (int m = 0; m < 8; ++m)
#pragma unroll
            for (int n = 0; n < 4; ++n)
#pragma unroll
                for (int r = 0; r < 4; ++r) {
                    const int row = mBase + wrow * 128 + m * 16 + quad * 4 + r;
                    dst[(long)row * 1024 + lcb + n * 16 + l16] =
                        (f16)(acc[m][n][r] + bvv[n]);
                }
    } else {
        // V: per-wave transpose through a private LDS region (64 e x 80 f16),
        // store 8 e-rows x 128 B per wave-instr along s. Intra-wave only.
        const int b = mBase >> 11, s0 = mBase & 2047;
        const int e0 = (nBase & 1023) + wcol * 64;
        f16* epiW = smem + wave * (64 * 80);
#pragma unroll
        for (int sb = 0; sb < 2; ++sb) {
#pragma unroll
            for (int m4 = 0; m4 < 4; ++m4)
#pragma unroll
                for (int n = 0; n < 4; ++n) {
                    f16x4v pk;
#pragma unroll
                    for (int r = 0; r < 4; ++r)
                        pk[r] = (f16)(acc[sb * 4 + m4][n][r] + bvv[n]);
                    *(f16x4v*)&epiW[(n * 16 + l16) * 80 + m4 * 16 + quad * 4] = pk;
                }
            asm volatile("s_waitcnt lgkmcnt(0)" ::: "memory");
#pragma unroll
            for (int it = 0; it < 8; ++it) {
                const int e = it * 8 + (lane >> 3);
                const f16x8 v = *(const f16x8*)&epiW[e * 80 + (lane & 7) * 8];
                *(f16x8*)(Vt16 + ((long)b * 1024 + e0 + e) * 2048 + s0 +
                          wrow * 128 + sb * 64 + (lane & 7) * 8) = v;
            }
        }
    }
}

// ============================================================================
// r9: scores (mode 2) ported to the same 256x256 8-phase loop.
// P[b][q][k] = exp((Q.K^T)/32) f16, causal-zeroed; rowsum atomics.
// Grid dim3(8,8,4); masked tiles (bx>by) early-return -> 144 live blocks
// (single round); masked=0 -> 256 blocks = exactly 1/CU.
// Causal skip granularity is 256 (mode3 reads cols < (by128+1)*128 <=
// (by256+1)*256, so skipped regions of P are never read).
// ============================================================================
__global__ __launch_bounds__(512, 2) void scores256(
    const f16* __restrict__ Q, const f16* __restrict__ K,
    f16* __restrict__ P, float* __restrict__ rowsum,
    const int* __restrict__ maskedp)
{
    const int masked = *maskedp;
    const int bx = blockIdx.x, by = blockIdx.y, bz = blockIdx.z;
    if (masked && bx > by) return;
    const int mBase = by * 256, nBase = bx * 256;

    GEMM256_SETUP

    const f16* Ab  = Q + (long)bz * (2048L * 1024);
    const f16* Btb = K + (long)bz * (2048L * 1024);
    const f16* pA  = Ab  + (long)(mBase + rowLane) * 1024 + cOff;
    const f16* pA1 = pA + 128 * 1024;
    const f16* pB  = Btb + (long)(nBase + rowLane) * 1024 + cOff;
    const f16* pB1 = pB + 128 * 1024;

    GEMM256_MAIN_LOOP;

    // ---- epilogue: exp(score/32), causal zero, f16 store, rowsum atomics ---
    f16* Crow = P + (long)bz * (2048L * 2048);
    float* rsb = rowsum + bz * 2048;
#pragma unroll
    for (int m = 0; m < 8; ++m) {
        float rs[4] = {0.f, 0.f, 0.f, 0.f};
#pragma unroll
        for (int n = 0; n < 4; ++n)
#pragma unroll
            for (int r = 0; r < 4; ++r) {
                const int row = mBase + wrow * 128 + m * 16 + quad * 4 + r;
                const int col = nBase + wcol * 64 + n * 16 + l16;
                float e = __expf(acc[m][n][r] * 0.03125f);
                if (masked && col > row) e = 0.f;   // only true on diag tiles
                const f16 hv = (f16)e;
                Crow[(long)row * 2048 + col] = hv;
                rs[r] += (float)hv;
            }
#pragma unroll
        for (int r = 0; r < 4; ++r) {
            float s = rs[r];
            s += __shfl_xor(s, 1);
            s += __shfl_xor(s, 2);
            s += __shfl_xor(s, 4);
            s += __shfl_xor(s, 8);
            if (l16 == 0) {
                const int row = mBase + wrow * 128 + m * 16 + quad * 4 + r;
                atomicAdd(&rsb[row], s);
            }
        }
    }
}

#undef STG
#undef RD_A
#undef RD_B2
#undef FENCE_MM
#undef VMC
#undef BAR
#undef GEMM256_MAIN_LOOP
#undef GEMM256_SETUP

// ============================================================================
// mode 3 (PV) unchanged from r7 -- next optimization target.
// C[m,n] = sum_k A[m,k] * Bt[n,k], tile 128 x 128, K-step 64 = 2 x BK32.
// MODE 3: 512 thr. out = (P @ V) / rowsum[q], fp32; K-loop causal-limited.
// ============================================================================
template <int MODE>
__global__ __launch_bounds__((MODE == 0) ? 256 : 512) void gemm_bt(
    const f16* __restrict__ A, long strideAb, int lda,
    const f16* __restrict__ Bt, long strideBb, int ldb,
    const float* __restrict__ b_q, const float* __restrict__ b_k,
    const float* __restrict__ b_v, float* __restrict__ rowsum,
    void* __restrict__ C0, void* __restrict__ C1, void* __restrict__ C2,
    long strideCb, int K,
    const int* __restrict__ maskedp)
{
    constexpr int NT  = (MODE == 0) ? 256 : 512;   // threads
    constexpr int NI  = (MODE == 0) ? 4 : 2;       // 16-row blocks per wave
    constexpr int RND = (128 * 32) / (NT * 8);     // staging rounds per subtile

    const int bx = blockIdx.x, bz = blockIdx.z;
    // heavy (long-K / unskipped) rows launch first for causal modes
    const int by = (MODE >= 2) ? (gridDim.y - 1 - blockIdx.y) : blockIdx.y;
    const int masked = maskedp ? *maskedp : 1;
    if (MODE == 2 && masked && bx > by) return;      // fully-masked tile
    int kmax = K;
    if (MODE == 3 && masked) kmax = min(K, (by + 1) * 128);

    A  += (long)bz * strideAb;
    Bt += (long)bz * strideBb;

    // two BK=32 sub-tiles of A (128x32) + two of B (128x32)
    __shared__ __align__(16) f16 smem[256 * 64];
    f16* sA = smem;                    // halves at h*4096
    f16* sB = smem + 128 * 64;

    const int tid  = threadIdx.x;
    const int wave = tid >> 6, lane = tid & 63;
    const int wrow = wave >> 1, wcol = wave & 1;
    const int quad = lane >> 4, l16 = lane & 15;
    const int mBase = by * 128, nBase = bx * 128;

    f32x4 acc[NI][4];
#pragma unroll
    for (int i = 0; i < NI; ++i)
#pragma unroll
        for (int j = 0; j < 4; ++j)
            acc[i][j] = (f32x4){0.f, 0.f, 0.f, 0.f};

    // pointer-bumped staging addresses (+64 f16 per outer iter)
    const f16* aP[RND];
    const f16* bP[RND];
#pragma unroll
    for (int r = 0; r < RND; ++r) {
        aP[r] = A  + (long)(mBase + ((r * NT + tid) >> 2)) * lda + ((tid * 8) & 31);
        bP[r] = Bt + (long)(nBase + ((r * NT + tid) >> 2)) * ldb + ((tid * 8) & 31);
    }
    const int ldsOff = wave * 512;

    const int nT = kmax >> 6;          // K-step 64
    for (int kt = 0; kt < nT; ++kt) {
#pragma unroll
        for (int h = 0; h < 2; ++h)
#pragma unroll
            for (int r = 0; r < RND; ++r) {
                async_ld16(aP[r] + h * 32, &sA[h * 4096 + r * (NT * 8) + ldsOff]);
                async_ld16(bP[r] + h * 32, &sB[h * 4096 + r * (NT * 8) + ldsOff]);
            }
#pragma unroll
        for (int r = 0; r < RND; ++r) { aP[r] += 64; bP[r] += 64; }
        __syncthreads();

#pragma unroll
        for (int h = 0; h < 2; ++h) {
            f16x8 af[NI], bf[4];
#pragma unroll
            for (int i = 0; i < NI; ++i)
                af[i] = *(const f16x8*)&sA[h * 4096 + (wrow * (16 * NI) + i * 16 + l16) * 32 + quad * 8];
#pragma unroll
            for (int j = 0; j < 4; ++j)
                bf[j] = *(const f16x8*)&sB[h * 4096 + (wcol * 64 + j * 16 + l16) * 32 + quad * 8];
#pragma unroll
            for (int i = 0; i < NI; ++i)
#pragma unroll
                for (int j = 0; j < 4; ++j)
                    acc[i][j] = __builtin_amdgcn_mfma_f32_16x16x32_f16(af[i], bf[j], acc[i][j], 0, 0, 0);
        }
        __syncthreads();
    }

    if (MODE == 2) {
        f16* Crow = (f16*)C0 + (long)bz * strideCb;
        float* rsb = rowsum + bz * 2048;
#pragma unroll
        for (int i = 0; i < NI; ++i) {
            float rs[4] = {0.f, 0.f, 0.f, 0.f};
#pragma unroll
            for (int j = 0; j < 4; ++j)
#pragma unroll
                for (int r = 0; r < 4; ++r) {
                    const int row = mBase + wrow * 32 + i * 16 + quad * 4 + r;
                    const int col = nBase + wcol * 64 + j * 16 + l16;
                    float e = __expf(acc[i][j][r] * 0.03125f);
                    if (masked && col > row) e = 0.f;
                    const f16 hv = (f16)e;
                    Crow[(long)row * 2048 + col] = hv;
                    rs[r] += (float)hv;
                }
#pragma unroll
            for (int r = 0; r < 4; ++r) {
                float s = rs[r];
                s += __shfl_xor(s, 1);
                s += __shfl_xor(s, 2);
                s += __shfl_xor(s, 4);
                s += __shfl_xor(s, 8);
                if (l16 == 0) {
                    const int row = mBase + wrow * 32 + i * 16 + quad * 4 + r;
                    atomicAdd(&rsb[row], s);
                }
            }
        }
    } else if (MODE == 3) {
        float* Crow = (float*)C0 + (long)bz * strideCb;
        const float* rsb = rowsum + bz * 2048;
#pragma unroll
        for (int i = 0; i < NI; ++i)
#pragma unroll
            for (int r = 0; r < 4; ++r) {
                const int row = mBase + wrow * 32 + i * 16 + quad * 4 + r;
                const float inv = 1.f / rsb[row];
#pragma unroll
                for (int j = 0; j < 4; ++j) {
                    const int col = nBase + wcol * 64 + j * 16 + l16;
                    Crow[(long)row * 1024 + col] = acc[i][j][r] * inv;
                }
            }
    }
}

__global__ void cvt_inp(const float* __restrict__ in, f16* __restrict__ out, int n4)
{
    const int i = blockIdx.x * blockDim.x + threadIdx.x;
    if (i >= n4) return;
    const float4 v = ((const float4*)in)[i];
    f16x4v o;
    o[0] = (f16)v.x; o[1] = (f16)v.y; o[2] = (f16)v.z; o[3] = (f16)v.w;
    ((f16x4v*)out)[i] = o;
}

// three 1024x1024 weight matrices -> contiguous f16 [3072][1024]
__global__ void cvt_w3(const float* __restrict__ W0, const float* __restrict__ W1,
                       const float* __restrict__ W2, f16* __restrict__ out)
{
    const int bxx = blockIdx.x;            // 3072 blocks
    const int which = bxx >> 10;
    const float* src = (which == 0) ? W0 : (which == 1) ? W1 : W2;
    const int i = (bxx & 1023) * 256 + threadIdx.x;
    const float4 v = ((const float4*)src)[i];
    f16x4v o;
    o[0] = (f16)v.x; o[1] = (f16)v.y; o[2] = (f16)v.z; o[3] = (f16)v.w;
    ((f16x4v*)(out + (long)which * 1024 * 1024))[i] = o;
}

extern "C" void kernel_launch(void* const* d_in, const int* in_sizes, int n_in,
                              void* d_out, int out_size, void* d_ws, size_t ws_size,
                              hipStream_t stream)
{
    const float* inp = (const float*)d_in[0];
    const int* masked = (const int*)d_in[1];
    const float* Wq = (const float*)d_in[2];
    const float* bq = (const float*)d_in[3];
    const float* Wk = (const float*)d_in[4];
    const float* bk = (const float*)d_in[5];
    const float* Wv = (const float*)d_in[6];
    const float* bv = (const float*)d_in[7];
    float* out = (float*)d_out;

    const int Bb = 4, S = 2048, E = 1024;
    const long nTok = (long)Bb * S;   // 8192

    // workspace (~102 MB). W3 segments must stay contiguous (one Bt operand).
    char* ws = (char*)d_ws;
    f16* inp16 = (f16*)ws;   ws += nTok * E * 2;         // 16 MB
    f16* W3    = (f16*)ws;   ws += (long)3 * E * E * 2;  //  6 MB
    f16* Q16   = (f16*)ws;   ws += nTok * E * 2;         // 16 MB
    f16* K16   = (f16*)ws;   ws += nTok * E * 2;         // 16 MB
    f16* Vt16  = (f16*)ws;   ws += nTok * E * 2;         // 16 MB ([b][e][s])
    f16* P16   = (f16*)ws;   ws += (long)Bb * S * S * 2; // 32 MB
    float* rsum = (float*)ws; ws += nTok * 4;            // 32 KB

    dim3 blk(256);

    hipMemsetAsync(rsum, 0, nTok * 4, stream);
    cvt_inp<<<(int)(nTok * E / 4 / 256), blk, 0, stream>>>(inp, inp16, (int)(nTok * E / 4));
    cvt_w3<<<3 * 1024, blk, 0, stream>>>(Wq, Wk, Wv, W3);

    // fused QKV: 256x256-tile 8-phase kernel (r8)
    qkv256<<<dim3(32 * 12), dim3(512), 0, stream>>>(
        inp16, W3, bq, bk, bv, Q16, K16, Vt16);

    // P = exp(QK^T/32): 256x256-tile 8-phase kernel (r9); masked tiles
    // early-return (144 live blocks, single round); rowsum atomics
    scores256<<<dim3(8, 8, 4), dim3(512), 0, stream>>>(
        Q16, K16, P16, rsum, masked);

    // out = (P @ V)/rowsum (128x128 tiles, 8-wave blocks, K causal-limited)
    gemm_bt<3><<<dim3(E / 128, S / 128, Bb), dim3(512), 0, stream>>>(
        P16, (long)S * S, S, Vt16, (long)E * S, S, nullptr, nullptr, nullptr, rsum,
        out, nullptr, nullptr, (long)S * E, S, masked);
}

// Round 3
// 240.259 us; speedup vs baseline: 1.1038x; 1.0163x over previous
//
#include <hip/hip_runtime.h>

typedef _Float16 f16;
typedef f16 f16x8 __attribute__((ext_vector_type(8)));
typedef f16 f16x4v __attribute__((ext_vector_type(4)));
typedef float f32x4 __attribute__((ext_vector_type(4)));

// async global->LDS, 16B per lane. LDS dest is wave-uniform base; HW scatters
// lane i's 16B to base + i*16.
__device__ __forceinline__ void async_ld16(const void* g, void* l) {
    __builtin_amdgcn_global_load_lds(
        (const __attribute__((address_space(1))) unsigned int*)g,
        (__attribute__((address_space(3))) unsigned int*)l, 16, 0, 0);
}

// ============================================================================
// 256x256-tile 8-phase GEMM loop (T1..T5), shared by qkv256 and scores256.
// Geometry: BM=BN=256, BK=64 (2 x kk-32 halves), 512 thr = 8 waves (2M x 4N),
// per-wave C = 128x64 = 8x4 frags of 16x16x32 f16 MFMA. LDS = 2 buf x
// (A 256x64 + B 256x64) f16 = 128 KiB. K = 1024 = 16 K-tiles, 2 per iter.
//
// T2 swizzle: LDS rows are 64 B; 16B-unit u of row holds global unit
// c = u ^ ((row>>1)&3); global_load_lds dest LINEAR, source col pre-swizzled
// (m173 both-sides rule). r8 measured: bank conflicts 6.55M -> 524K.
//
// Schedule: 8 phases / 2 K-tiles; stage one (buf,op,khalf) region per phase;
// counted s_waitcnt vmcnt(4) at p3/p7 ONLY (2 half-tile regions stay in
// flight across each boundary, never drained mid-loop).
// ============================================================================

// region byte offsets: buf b: b*65536; op (A=0,B=1): op*32768; k-half: kh*16384
#define STG(b, op, kh, P, P1, tOff) do {                                        \
    char* d_ = (char*)smem + (b) * 65536 + (op) * 32768 + (kh) * 16384 + stgBase; \
    async_ld16((P)  + (tOff) * 64 + (kh) * 32, d_);                             \
    async_ld16((P1) + (tOff) * 64 + (kh) * 32, d_ + 8192);                      \
} while (0)
#define RD_A(b, kk) do {                                                        \
    const char* s_ = (const char*)smem + (b) * 65536 + (kk) * 16384 + aOff;     \
    _Pragma("unroll") for (int m_ = 0; m_ < 8; ++m_)                            \
        af[m_] = *(const f16x8*)(s_ + m_ * 1024);                               \
} while (0)
#define RD_B2(b, kk, n0_) do {                                                  \
    const char* s_ = (const char*)smem + (b) * 65536 + 32768 + (kk) * 16384 + bOff; \
    bf[(n0_)]     = *(const f16x8*)(s_ + ((n0_)) * 1024);                       \
    bf[(n0_) + 1] = *(const f16x8*)(s_ + ((n0_) + 1) * 1024);                   \
} while (0)
// barrier; lgkmcnt(0)+sched_barrier (rule #18); setprio'd 16-MFMA cluster (T5)
#define FENCE_MM(n0_) do {                                                      \
    __builtin_amdgcn_s_barrier();                                               \
    asm volatile("s_waitcnt lgkmcnt(0)" ::: "memory");                          \
    __builtin_amdgcn_sched_barrier(0);                                          \
    __builtin_amdgcn_s_setprio(1);                                              \
    _Pragma("unroll") for (int m_ = 0; m_ < 8; ++m_) {                          \
        acc[m_][(n0_)]     = __builtin_amdgcn_mfma_f32_16x16x32_f16(af[m_], bf[(n0_)],     acc[m_][(n0_)],     0, 0, 0); \
        acc[m_][(n0_) + 1] = __builtin_amdgcn_mfma_f32_16x16x32_f16(af[m_], bf[(n0_) + 1], acc[m_][(n0_) + 1], 0, 0, 0); \
    }                                                                           \
    __builtin_amdgcn_s_setprio(0);                                              \
} while (0)
#define VMC(n) asm volatile("s_waitcnt vmcnt(" #n ")" ::: "memory")
#define BAR __builtin_amdgcn_s_barrier()

// 7 steady iterations + peeled tail = 16 K-tiles (K=1024, lda=ldb=1024).
#define GEMM256_MAIN_LOOP do {                                                  \
    STG(0, 0, 0, pA, pA1, 0); STG(0, 1, 0, pB, pB1, 0);                         \
    STG(0, 0, 1, pA, pA1, 0); STG(0, 1, 1, pB, pB1, 0);                         \
    STG(1, 0, 0, pA, pA1, 1); STG(1, 1, 0, pB, pB1, 1);                         \
    VMC(4);                                                                     \
    BAR;                                                                        \
    _Pragma("unroll 1")                                                         \
    for (int i_ = 0; i_ < 7; ++i_) {                                            \
        RD_A(0, 0); RD_B2(0, 0, 0); STG(1, 0, 1, pA, pA1, 1);   /* p0 */        \
        FENCE_MM(0); BAR;                                                       \
        RD_B2(0, 0, 2);             STG(1, 1, 1, pB, pB1, 1);   /* p1 */        \
        FENCE_MM(2); BAR;                                                       \
        RD_A(0, 1); RD_B2(0, 1, 0); STG(0, 0, 0, pA, pA1, 2);   /* p2 */        \
        FENCE_MM(0); BAR;                                                       \
        RD_B2(0, 1, 2);             STG(0, 1, 0, pB, pB1, 2);   /* p3 */        \
        FENCE_MM(2); VMC(4); BAR;                                               \
        RD_A(1, 0); RD_B2(1, 0, 0); STG(0, 0, 1, pA, pA1, 2);   /* p4 */        \
        FENCE_MM(0); BAR;                                                       \
        RD_B2(1, 0, 2);             STG(0, 1, 1, pB, pB1, 2);   /* p5 */        \
        FENCE_MM(2); BAR;                                                       \
        RD_A(1, 1); RD_B2(1, 1, 0); STG(1, 0, 0, pA, pA1, 3);   /* p6 */        \
        FENCE_MM(0); BAR;                                                       \
        RD_B2(1, 1, 2);             STG(1, 1, 0, pB, pB1, 3);   /* p7 */        \
        FENCE_MM(2); VMC(4); BAR;                                               \
        pA += 128; pA1 += 128; pB += 128; pB1 += 128;                           \
    }                                                                           \
    RD_A(0, 0); RD_B2(0, 0, 0); STG(1, 0, 1, pA, pA1, 1);                       \
    FENCE_MM(0); BAR;                                                           \
    RD_B2(0, 0, 2);             STG(1, 1, 1, pB, pB1, 1);                       \
    FENCE_MM(2); BAR;                                                           \
    RD_A(0, 1); RD_B2(0, 1, 0);                                                 \
    FENCE_MM(0); BAR;                                                           \
    RD_B2(0, 1, 2);                                                             \
    FENCE_MM(2); VMC(0); BAR;                                                   \
    RD_A(1, 0); RD_B2(1, 0, 0);                                                 \
    FENCE_MM(0); BAR;                                                           \
    RD_B2(1, 0, 2);                                                             \
    FENCE_MM(2); BAR;                                                           \
    RD_A(1, 1); RD_B2(1, 1, 0);                                                 \
    FENCE_MM(0); BAR;                                                           \
    RD_B2(1, 1, 2);                                                             \
    FENCE_MM(2); BAR;  /* trailing barrier also guards smem reuse below */      \
} while (0)

// common per-thread index setup (names used by the macros above)
#define GEMM256_SETUP                                                           \
    __shared__ __align__(16) f16 smem[65536];  /* 128 KiB */                    \
    const int tid = threadIdx.x;                                                \
    const int wave = tid >> 6, lane = tid & 63;                                 \
    const int wrow = wave >> 2, wcol = wave & 3;                                \
    const int quad = lane >> 4, l16 = lane & 15;                                \
    const int rowLane = tid >> 2;                                               \
    const int cOff = ((tid & 3) ^ ((tid >> 3) & 3)) * 8;                        \
    const int stgBase = wave * 1024;                                            \
    const int swz  = (quad ^ ((l16 >> 1) & 3)) * 16;                            \
    const int aOff = (wrow * 128 + l16) * 64 + swz;                             \
    const int bOff = (wcol * 64 + l16) * 64 + swz;                              \
    f32x4 acc[8][4];                                                            \
    _Pragma("unroll") for (int m_i = 0; m_i < 8; ++m_i)                         \
        _Pragma("unroll") for (int n_i = 0; n_i < 4; ++n_i)                     \
            acc[m_i][n_i] = (f32x4){0.f, 0.f, 0.f, 0.f};                        \
    f16x8 af[8], bf[4];

// ============================================================================
// r8: fused QKV projection. C[8192 x 3072] = inp16 @ W3^T + bias; segment
// epilogues: Q/K row-major f16 (+bias), V transposed to [b][e][s] via LDS.
// KNOWN ISSUE (r9 post-mortem): grid 384 @ 1 block/CU = 1.5 rounds -> 2
// serialized rounds (33% tail). Fix deferred to keep rounds single-change.
// ============================================================================
__global__ __launch_bounds__(512, 2) void qkv256(
    const f16* __restrict__ A, const f16* __restrict__ Bt,
    const float* __restrict__ b_q, const float* __restrict__ b_k,
    const float* __restrict__ b_v,
    f16* __restrict__ Q16, f16* __restrict__ K16, f16* __restrict__ Vt16)
{
    // T1: XCD-aware bijective swizzle (grid 384, 384 % 8 == 0).
    int bid = blockIdx.x;
    bid = (bid & 7) * 48 + (bid >> 3);
    const int by = bid / 12, bx = bid - by * 12;
    const int mBase = by * 256, nBase = bx * 256;

    GEMM256_SETUP

    const f16* pA  = A  + (long)(mBase + rowLane) * 1024 + cOff;
    const f16* pA1 = pA + 128 * 1024;
    const f16* pB  = Bt + (long)(nBase + rowLane) * 1024 + cOff;
    const f16* pB1 = pB + 128 * 1024;

    GEMM256_MAIN_LOOP;

    // ---- epilogue. C/D layout: col = lane&15, row = quad*4 + reg  [m89] ----
    const int seg = nBase >> 10;
    const float* bs = (seg == 0) ? b_q : (seg == 1) ? b_k : b_v;
    const int lcb = (nBase & 1023) + wcol * 64;
    float bvv[4];
#pragma unroll
    for (int n = 0; n < 4; ++n) bvv[n] = bs[lcb + n * 16 + l16];

    if (seg < 2) {
        f16* dst = (seg == 0) ? Q16 : K16;
#pragma unroll
        for (int m = 0; m < 8; ++m)
#pragma unroll
            for (int n = 0; n < 4; ++n)
#pragma unroll
                for (int r = 0; r < 4; ++r) {
                    const int row = mBase + wrow * 128 + m * 16 + quad * 4 + r;
                    dst[(long)row * 1024 + lcb + n * 16 + l16] =
                        (f16)(acc[m][n][r] + bvv[n]);
                }
    } else {
        // V: per-wave transpose through a private LDS region (64 e x 80 f16),
        // store 8 e-rows x 128 B per wave-instr along s. Intra-wave only.
        const int b = mBase >> 11, s0 = mBase & 2047;
        const int e0 = (nBase & 1023) + wcol * 64;
        f16* epiW = smem + wave * (64 * 80);
#pragma unroll
        for (int sb = 0; sb < 2; ++sb) {
#pragma unroll
            for (int m4 = 0; m4 < 4; ++m4)
#pragma unroll
                for (int n = 0; n < 4; ++n) {
                    f16x4v pk;
#pragma unroll
                    for (int r = 0; r < 4; ++r)
                        pk[r] = (f16)(acc[sb * 4 + m4][n][r] + bvv[n]);
                    *(f16x4v*)&epiW[(n * 16 + l16) * 80 + m4 * 16 + quad * 4] = pk;
                }
            asm volatile("s_waitcnt lgkmcnt(0)" ::: "memory");
#pragma unroll
            for (int it = 0; it < 8; ++it) {
                const int e = it * 8 + (lane >> 3);
                const f16x8 v = *(const f16x8*)&epiW[e * 80 + (lane & 7) * 8];
                *(f16x8*)(Vt16 + ((long)b * 1024 + e0 + e) * 2048 + s0 +
                          wrow * 128 + sb * 64 + (lane & 7) * 8) = v;
            }
        }
    }
}

// ============================================================================
// r9: scores (mode 2) on the 256x256 8-phase loop.
// P[b][q][k] = exp((Q.K^T)/32) f16, causal-zeroed; rowsum atomics.
// Grid dim3(8,8,4); masked tiles (bx>by) early-return -> 144 live blocks
// (single round); masked=0 -> 256 blocks = exactly 1/CU.
// ============================================================================
__global__ __launch_bounds__(512, 2) void scores256(
    const f16* __restrict__ Q, const f16* __restrict__ K,
    f16* __restrict__ P, float* __restrict__ rowsum,
    const int* __restrict__ maskedp)
{
    const int masked = *maskedp;
    const int bx = blockIdx.x, by = blockIdx.y, bz = blockIdx.z;
    if (masked && bx > by) return;
    const int mBase = by * 256, nBase = bx * 256;

    GEMM256_SETUP

    const f16* Ab  = Q + (long)bz * (2048L * 1024);
    const f16* Btb = K + (long)bz * (2048L * 1024);
    const f16* pA  = Ab  + (long)(mBase + rowLane) * 1024 + cOff;
    const f16* pA1 = pA + 128 * 1024;
    const f16* pB  = Btb + (long)(nBase + rowLane) * 1024 + cOff;
    const f16* pB1 = pB + 128 * 1024;

    GEMM256_MAIN_LOOP;

    // ---- epilogue: exp(score/32), causal zero, f16 store, rowsum atomics ---
    f16* Crow = P + (long)bz * (2048L * 2048);
    float* rsb = rowsum + bz * 2048;
#pragma unroll
    for (int m = 0; m < 8; ++m) {
        float rs[4] = {0.f, 0.f, 0.f, 0.f};
#pragma unroll
        for (int n = 0; n < 4; ++n)
#pragma unroll
            for (int r = 0; r < 4; ++r) {
                const int row = mBase + wrow * 128 + m * 16 + quad * 4 + r;
                const int col = nBase + wcol * 64 + n * 16 + l16;
                float e = __expf(acc[m][n][r] * 0.03125f);
                if (masked && col > row) e = 0.f;   // only true on diag tiles
                const f16 hv = (f16)e;
                Crow[(long)row * 2048 + col] = hv;
                rs[r] += (float)hv;
            }
#pragma unroll
        for (int r = 0; r < 4; ++r) {
            float s = rs[r];
            s += __shfl_xor(s, 1);
            s += __shfl_xor(s, 2);
            s += __shfl_xor(s, 4);
            s += __shfl_xor(s, 8);
            if (l16 == 0) {
                const int row = mBase + wrow * 128 + m * 16 + quad * 4 + r;
                atomicAdd(&rsb[row], s);
            }
        }
    }
}

#undef STG
#undef RD_A
#undef RD_B2
#undef FENCE_MM
#undef GEMM256_MAIN_LOOP
#undef GEMM256_SETUP

// ============================================================================
// r10: PV (mode 3) ported to an 8-phase-style deep-pipelined structure.
// out[b][q][e] = (P @ V) / rowsum[q], fp32.  BM=256 (q) x BN=128 (e),
// BK=64 (2 x kk-32), 512 thr = 8 waves (2M x 4N), wave C = 128x32 = 8x2
// frags. LDS = 2 buf x (A 256x64 + B 128x64) f16 = 96 KiB.
// Grid (8,8,4) = 256 blocks = exactly 1 per CU, single round (fixes old
// mode3's wave-starved 128^2 structure, est ~110 us at ~10% util).
// Causal: kmax = (by+1)*256, matching scores256's 256-granular tile skip.
// 4 phases / 2 K-tiles: each phase = {10 ds_read_b128 | stage 3 loads ->
// barrier -> lgkmcnt(0) -> 16 MFMA (setprio) -> vmcnt(6) -> barrier}.
// vmcnt ledger: 3 loads/phase issued, vmcnt(6) keeps 2 region-groups in
// flight; each group lands 2 phases (>=400 cyc) after issue; never 0.
// ============================================================================
#define PSTG_A(b, kh, tOff) do {                                                \
    char* d_ = (char*)smem + (b) * 49152 + (kh) * 16384 + stgBase;              \
    async_ld16(pA  + (tOff) * 64 + (kh) * 32, d_);                              \
    async_ld16(pA1 + (tOff) * 64 + (kh) * 32, d_ + 8192);                       \
} while (0)
#define PSTG_B(b, kh, tOff) do {                                                \
    char* d_ = (char*)smem + (b) * 49152 + 32768 + (kh) * 8192 + stgBase;       \
    async_ld16(pB + (tOff) * 64 + (kh) * 32, d_);                               \
} while (0)
#define PRD(b, kk) do {                                                         \
    const char* sa_ = (const char*)smem + (b) * 49152 + (kk) * 16384 + aOff;    \
    _Pragma("unroll") for (int m_ = 0; m_ < 8; ++m_)                            \
        af[m_] = *(const f16x8*)(sa_ + m_ * 1024);                              \
    const char* sb_ = (const char*)smem + (b) * 49152 + 32768 + (kk) * 8192 + bOff; \
    bf[0] = *(const f16x8*)(sb_);                                               \
    bf[1] = *(const f16x8*)(sb_ + 1024);                                        \
} while (0)
#define PFENCE do {                                                             \
    __builtin_amdgcn_s_barrier();                                               \
    asm volatile("s_waitcnt lgkmcnt(0)" ::: "memory");                          \
    __builtin_amdgcn_sched_barrier(0);                                          \
    __builtin_amdgcn_s_setprio(1);                                              \
    _Pragma("unroll") for (int m_ = 0; m_ < 8; ++m_) {                          \
        acc[m_][0] = __builtin_amdgcn_mfma_f32_16x16x32_f16(af[m_], bf[0], acc[m_][0], 0, 0, 0); \
        acc[m_][1] = __builtin_amdgcn_mfma_f32_16x16x32_f16(af[m_], bf[1], acc[m_][1], 0, 0, 0); \
    }                                                                           \
    __builtin_amdgcn_s_setprio(0);                                              \
} while (0)

__global__ __launch_bounds__(512, 2) void pv256(
    const f16* __restrict__ P, const f16* __restrict__ Vt,
    const float* __restrict__ rowsum, float* __restrict__ out,
    const int* __restrict__ maskedp)
{
    const int masked = *maskedp;
    const int bx = blockIdx.x, by = blockIdx.y, bz = blockIdx.z;
    const int mBase = by * 256, nBase = bx * 128;
    const int nIter = masked ? (by + 1) * 2 : 16;   // K-tile pairs; >= 2

    __shared__ __align__(16) f16 smem[49152];  // 96 KiB
    const int tid = threadIdx.x;
    const int wave = tid >> 6, lane = tid & 63;
    const int wrow = wave >> 2, wcol = wave & 3;
    const int quad = lane >> 4, l16 = lane & 15;
    const int rowLane = tid >> 2;
    const int cOff = ((tid & 3) ^ ((tid >> 3) & 3)) * 8;
    const int stgBase = wave * 1024;
    const int swz  = (quad ^ ((l16 >> 1) & 3)) * 16;
    const int aOff = (wrow * 128 + l16) * 64 + swz;
    const int bOff = (wcol * 32 + l16) * 64 + swz;

    const f16* Pb = P  + (long)bz * (2048L * 2048);
    const f16* Vb = Vt + (long)bz * (1024L * 2048);
    const f16* pA  = Pb + (long)(mBase + rowLane) * 2048 + cOff;
    const f16* pA1 = pA + 128 * 2048;
    const f16* pB  = Vb + (long)(nBase + rowLane) * 2048 + cOff;

    f32x4 acc[8][2];
#pragma unroll
    for (int m = 0; m < 8; ++m) {
        acc[m][0] = (f32x4){0.f, 0.f, 0.f, 0.f};
        acc[m][1] = (f32x4){0.f, 0.f, 0.f, 0.f};
    }
    f16x8 af[8], bf[2];

    // prologue: tile0 both halves + tile1 k0; wait tile0 (6 oldest of 9)
    PSTG_A(0, 0, 0); PSTG_B(0, 0, 0);
    PSTG_A(0, 1, 0); PSTG_B(0, 1, 0);
    PSTG_A(1, 0, 1); PSTG_B(1, 0, 1);
    VMC(3);
    BAR;

#pragma unroll 1
    for (int i = 0; i < nIter - 1; ++i) {
        PRD(0, 0); PSTG_A(1, 1, 1); PSTG_B(1, 1, 1);   // p0: (t+1).k1
        PFENCE; VMC(6); BAR;
        PRD(0, 1); PSTG_A(0, 0, 2); PSTG_B(0, 0, 2);   // p1: (t+2).k0
        PFENCE; VMC(6); BAR;
        PRD(1, 0); PSTG_A(0, 1, 2); PSTG_B(0, 1, 2);   // p2: (t+2).k1
        PFENCE; VMC(6); BAR;
        PRD(1, 1); PSTG_A(1, 0, 3); PSTG_B(1, 0, 3);   // p3: (t+3).k0
        PFENCE; VMC(6); BAR;
        pA += 128; pA1 += 128; pB += 128;
    }
    // tail: tiles T-2 (b0), T-1 (b1); only (T-1).k1 left to stage
    PRD(0, 0); PSTG_A(1, 1, 1); PSTG_B(1, 1, 1);
    PFENCE; VMC(6); BAR;
    PRD(0, 1);
    PFENCE; VMC(3); BAR;
    PRD(1, 0);
    PFENCE; VMC(0); BAR;
    PRD(1, 1);
    PFENCE;

    // ---- epilogue: out = acc / rowsum[row], fp32 coalesced 64B/quarter-wave
    const float* rsb = rowsum + bz * 2048;
    float* ob = out + (long)bz * (2048L * 1024);
#pragma unroll
    for (int m = 0; m < 8; ++m)
#pragma unroll
        for (int r = 0; r < 4; ++r) {
            const int row = mBase + wrow * 128 + m * 16 + quad * 4 + r;
            const float inv = 1.f / rsb[row];
#pragma unroll
            for (int n = 0; n < 2; ++n) {
                const int col = nBase + wcol * 32 + n * 16 + l16;
                ob[(long)row * 1024 + col] = acc[m][n][r] * inv;
            }
        }
}

#undef PSTG_A
#undef PSTG_B
#undef PRD
#undef PFENCE
#undef VMC
#undef BAR

__global__ void cvt_inp(const float* __restrict__ in, f16* __restrict__ out, int n4)
{
    const int i = blockIdx.x * blockDim.x + threadIdx.x;
    if (i >= n4) return;
    const float4 v = ((const float4*)in)[i];
    f16x4v o;
    o[0] = (f16)v.x; o[1] = (f16)v.y; o[2] = (f16)v.z; o[3] = (f16)v.w;
    ((f16x4v*)out)[i] = o;
}

// three 1024x1024 weight matrices -> contiguous f16 [3072][1024]
__global__ void cvt_w3(const float* __restrict__ W0, const float* __restrict__ W1,
                       const float* __restrict__ W2, f16* __restrict__ out)
{
    const int bxx = blockIdx.x;            // 3072 blocks
    const int which = bxx >> 10;
    const float* src = (which == 0) ? W0 : (which == 1) ? W1 : W2;
    const int i = (bxx & 1023) * 256 + threadIdx.x;
    const float4 v = ((const float4*)src)[i];
    f16x4v o;
    o[0] = (f16)v.x; o[1] = (f16)v.y; o[2] = (f16)v.z; o[3] = (f16)v.w;
    ((f16x4v*)(out + (long)which * 1024 * 1024))[i] = o;
}

extern "C" void kernel_launch(void* const* d_in, const int* in_sizes, int n_in,
                              void* d_out, int out_size, void* d_ws, size_t ws_size,
                              hipStream_t stream)
{
    const float* inp = (const float*)d_in[0];
    const int* masked = (const int*)d_in[1];
    const float* Wq = (const float*)d_in[2];
    const float* bq = (const float*)d_in[3];
    const float* Wk = (const float*)d_in[4];
    const float* bk = (const float*)d_in[5];
    const float* Wv = (const float*)d_in[6];
    const float* bv = (const float*)d_in[7];
    float* out = (float*)d_out;

    const int Bb = 4, S = 2048, E = 1024;
    const long nTok = (long)Bb * S;   // 8192

    // workspace (~102 MB). W3 segments must stay contiguous (one Bt operand).
    char* ws = (char*)d_ws;
    f16* inp16 = (f16*)ws;   ws += nTok * E * 2;         // 16 MB
    f16* W3    = (f16*)ws;   ws += (long)3 * E * E * 2;  //  6 MB
    f16* Q16   = (f16*)ws;   ws += nTok * E * 2;         // 16 MB
    f16* K16   = (f16*)ws;   ws += nTok * E * 2;         // 16 MB
    f16* Vt16  = (f16*)ws;   ws += nTok * E * 2;         // 16 MB ([b][e][s])
    f16* P16   = (f16*)ws;   ws += (long)Bb * S * S * 2; // 32 MB
    float* rsum = (float*)ws; ws += nTok * 4;            // 32 KB

    dim3 blk(256);

    hipMemsetAsync(rsum, 0, nTok * 4, stream);
    cvt_inp<<<(int)(nTok * E / 4 / 256), blk, 0, stream>>>(inp, inp16, (int)(nTok * E / 4));
    cvt_w3<<<3 * 1024, blk, 0, stream>>>(Wq, Wk, Wv, W3);

    // fused QKV: 256x256-tile 8-phase kernel (r8)
    qkv256<<<dim3(32 * 12), dim3(512), 0, stream>>>(
        inp16, W3, bq, bk, bv, Q16, K16, Vt16);

    // P = exp(QK^T/32): 256x256-tile 8-phase kernel (r9)
    scores256<<<dim3(8, 8, 4), dim3(512), 0, stream>>>(
        Q16, K16, P16, rsum, masked);

    // out = (P @ V)/rowsum: 256x128-tile 4-phase deep-pipelined (r10)
    pv256<<<dim3(8, 8, 4), dim3(512), 0, stream>>>(
        P16, Vt16, rsum, out, masked);
}